// Round 5
// baseline (36.201 us; speedup 1.0000x reference)
//
#include <hip/hip_runtime.h>

#define L 8192
#define ATT 1024
#define NPREV 8
#define NBLK 256   // K2 blocks, 32 rows each
#define NFIN 72    // finalize blocks: 64 for c, 8 for w-scale

__device__ inline float fast_tanh(float x) {
    // tanh(x) = 1 - 2/(exp(2x)+1); saturates correctly
    float e = __expf(2.0f * x);
    return 1.0f - 2.0f / (e + 1.0f);
}

// K1: 256 blocks x 256 thr; wave-per-output matvec.
// bd[a] = dot(dec_z, mlp_dec_w[a,:]) + mlp_dec_b[a] + wvec_b[a]; also resets ctr.
__global__ __launch_bounds__(256) void k_matvec(
    const float* __restrict__ dec_z, const float* __restrict__ mlp_dec_w,
    const float* __restrict__ mlp_dec_b, const float* __restrict__ wvec_b,
    float* __restrict__ bd, unsigned* __restrict__ ctr)
{
    int b = blockIdx.x, t = threadIdx.x;
    if (b == 0 && t == 0) *ctr = 0u;  // visible to K2 via kernel boundary
    int wave = t >> 6, lane = t & 63;
    int a = b * 4 + wave;
    const float4* wrow = (const float4*)(mlp_dec_w + (size_t)a * ATT);
    const float4* dz   = (const float4*)dec_z;
    float s = 0.f;
    #pragma unroll
    for (int k = 0; k < 4; ++k) {
        float4 wv = wrow[lane + 64 * k];
        float4 zv = dz[lane + 64 * k];
        s += wv.x * zv.x + wv.y * zv.y + wv.z * zv.z + wv.w * zv.w;
    }
    #pragma unroll
    for (int off = 32; off; off >>= 1) s += __shfl_down(s, off, 64);
    if (lane == 0) bd[a] = s + mlp_dec_b[a] + wvec_b[a];
}

// K2: 256 blocks x 1024 thr. Per block: local cov+att copy -> per-wave score(2 rows)
// + ctx accumulate -> LDS combine -> partial/usum -> arrive(ctr).
// Blocks b<NFIN spin until all arrived, then finalize (c and w-scale) in-kernel.
__global__ __launch_bounds__(1024) void k_main(
    const float* __restrict__ att_prev, const float* __restrict__ pre_enc,
    const float* __restrict__ enc_h, const float* __restrict__ wvec_w,
    const float* __restrict__ bd, const float* __restrict__ gvec_w,
    const float* __restrict__ gvec_b, const float* __restrict__ mask,
    float* __restrict__ out_att, float* __restrict__ out_c,
    float* __restrict__ usum, float* __restrict__ partial,
    unsigned* __restrict__ ctr)
{
    __shared__ float cov_s[32];
    __shared__ float uw[16];
    __shared__ float lds[8 * 1024];
    int t = threadIdx.x, b = blockIdx.x;
    int base = b * 32;
    int wave = t >> 6, lane = t & 63;
    float* out_w = out_att + NPREV * L;

    // phase 0: this block's 32 columns of att_prev: copy + coverage
    if (t < 32) {
        float s = 0.f;
        #pragma unroll
        for (int p = 0; p < NPREV; ++p) {
            float v = att_prev[p * L + base + t];
            out_att[p * L + base + t] = v;
            s += v;
        }
        cov_s[t] = s;
    }

    // broadcast vectors into registers (16 att-elems per lane)
    const float4* ww  = (const float4*)wvec_w;
    const float4* bdv = (const float4*)bd;
    const float4* gw  = (const float4*)gvec_w;
    float4 W4[4], BD4[4], G4[4];
    #pragma unroll
    for (int k = 0; k < 4; ++k) {
        W4[k]  = ww[lane + 64 * k];
        BD4[k] = bdv[lane + 64 * k];
        G4[k]  = gw[lane + 64 * k];
    }
    float gb = gvec_b[0];
    __syncthreads();

    // phase 1: each wave scores 2 rows and accumulates their enc_h columns
    const float4* enc = (const float4*)enc_h;
    float4 acc[4] = {};
    float us_w = 0.f;
    #pragma unroll
    for (int rr = 0; rr < 2; ++rr) {
        int r = wave * 2 + rr;
        int l = base + r;
        float cv = cov_s[r];
        const float4* row = (const float4*)(pre_enc + (size_t)l * ATT);
        float s = 0.f;
        #pragma unroll
        for (int k = 0; k < 4; ++k) {
            float4 pe = row[lane + 64 * k];
            s += fast_tanh(fmaf(cv, W4[k].x, BD4[k].x) + pe.x) * G4[k].x;
            s += fast_tanh(fmaf(cv, W4[k].y, BD4[k].y) + pe.y) * G4[k].y;
            s += fast_tanh(fmaf(cv, W4[k].z, BD4[k].z) + pe.z) * G4[k].z;
            s += fast_tanh(fmaf(cv, W4[k].w, BD4[k].w) + pe.w) * G4[k].w;
        }
        #pragma unroll
        for (int off = 32; off; off >>= 1) s += __shfl_xor(s, off, 64);
        // |2(s+gb+mask)| <= 2*sum|gvec_w| ~ 33 -> exp safe in f32, no max pass
        float uv = __expf(2.0f * (s + gb + mask[l]));
        if (lane == 0) { out_w[l] = uv; us_w += uv; }
        #pragma unroll
        for (int k = 0; k < 4; ++k) {
            float4 v = enc[(size_t)l * 256 + k * 64 + lane];
            acc[k].x += uv * v.x; acc[k].y += uv * v.y;
            acc[k].z += uv * v.z; acc[k].w += uv * v.w;
        }
    }
    if (lane == 0) uw[wave] = us_w;

    // cross-wave combine: waves 8..15 stage, waves 0..7 add, then tree over 8
    float4* la = (float4*)lds;
    if (wave >= 8) {
        #pragma unroll
        for (int k = 0; k < 4; ++k)
            la[(wave - 8) * 256 + k * 64 + lane] = acc[k];
    }
    __syncthreads();
    if (wave < 8) {
        #pragma unroll
        for (int k = 0; k < 4; ++k) {
            float4 o = la[wave * 256 + k * 64 + lane];
            o.x += acc[k].x; o.y += acc[k].y;
            o.z += acc[k].z; o.w += acc[k].w;
            la[wave * 256 + k * 64 + lane] = o;
        }
    }
    __syncthreads();
    {
        float s = 0.f;
        #pragma unroll
        for (int w = 0; w < 8; ++w) s += lds[w * 1024 + t];
        partial[(size_t)b * 1024 + t] = s;
    }
    if (t == 0) {
        float s = 0.f;
        #pragma unroll
        for (int w = 0; w < 16; ++w) s += uw[w];
        usum[b] = s;
    }
    __syncthreads();               // all global writes of this block drained
    if (t == 0) {
        __threadfence();           // device-scope release
        atomicAdd(ctr, 1u);        // arrive
    }
    if (b >= NFIN) return;

    // finalize blocks: wait for all arrivals (spinners < capacity: deadlock-free)
    if (t == 0) {
        while (__hip_atomic_load(ctr, __ATOMIC_RELAXED, __HIP_MEMORY_SCOPE_AGENT) < NBLK)
            __builtin_amdgcn_s_sleep(1);
        __threadfence();           // device-scope acquire
    }
    __syncthreads();

    // every wave computes inv(total) redundantly (usum is L2-hot)
    float v = usum[lane] + usum[lane + 64] + usum[lane + 128] + usum[lane + 192];
    #pragma unroll
    for (int off = 32; off; off >>= 1) v += __shfl_xor(v, off, 64);
    float inv = 1.0f / v;

    if (b < 64) {
        // 16 columns per block; t = r0*16 + jl; sum 256 partial rows per column
        int jl = t & 15, r0 = t >> 4;
        int j = b * 16 + jl;
        float s = 0.f;
        #pragma unroll
        for (int i = 0; i < 4; ++i)
            s += partial[(size_t)(r0 + 64 * i) * 1024 + j];
        lds[t] = s;
        __syncthreads();
        if (t < 512) lds[t] += lds[t + 512];
        __syncthreads();
        if (t < 256) lds[t] += lds[t + 256];
        __syncthreads();
        if (t < 128) lds[t] += lds[t + 128];
        __syncthreads();
        if (t < 64)  lds[t] += lds[t + 64];
        __syncthreads();
        if (t < 32)  lds[t] += lds[t + 32];
        __syncthreads();
        if (t < 16)  out_c[b * 16 + t] = (lds[t] + lds[t + 16]) * inv;
    } else {
        int l = (b - 64) * 1024 + t;
        out_w[l] *= inv;
    }
}

extern "C" void kernel_launch(void* const* d_in, const int* in_sizes, int n_in,
                              void* d_out, int out_size, void* d_ws, size_t ws_size,
                              hipStream_t stream) {
    const float* dec_z     = (const float*)d_in[0];
    const float* att_prev  = (const float*)d_in[1];
    const float* pre_enc   = (const float*)d_in[2];
    const float* enc_h     = (const float*)d_in[3];
    const float* mask      = (const float*)d_in[4];
    const float* wvec_w    = (const float*)d_in[5];
    const float* wvec_b    = (const float*)d_in[6];
    const float* mlp_dec_w = (const float*)d_in[7];
    const float* mlp_dec_b = (const float*)d_in[8];
    const float* gvec_w    = (const float*)d_in[9];
    const float* gvec_b    = (const float*)d_in[10];

    float* out     = (float*)d_out;
    float* out_c   = out;          // [1024]
    float* out_att = out + 1024;   // [9*8192]

    float* ws      = (float*)d_ws;
    float* bd      = ws;                        // 1024
    float* usum    = ws + 1024;                 // 256
    float* partial = ws + 1024 + 256;           // 256*1024 (16B-aligned: 5120B)
    unsigned* ctr  = (unsigned*)(ws + 1024 + 256 + 256 * 1024);

    k_matvec<<<256, 256, 0, stream>>>(dec_z, mlp_dec_w, mlp_dec_b, wvec_b, bd, ctr);
    k_main<<<NBLK, 1024, 0, stream>>>(att_prev, pre_enc, enc_h, wvec_w, bd,
                                      gvec_w, gvec_b, mask,
                                      out_att, out_c, usum, partial, ctr);
}

// Round 6
// 28.241 us; speedup vs baseline: 1.2819x; 1.2819x over previous
//
#include <hip/hip_runtime.h>

#define L 8192
#define ATT 1024
#define NPREV 8
#define K2B 2048   // K2 blocks, 4 rows each -> 8 blocks/CU, full wave occupancy

__device__ inline float fast_tanh(float x) {
    // tanh(x) = 1 - 2/(exp(2x)+1); saturates correctly
    float e = __expf(2.0f * x);
    return 1.0f - 2.0f / (e + 1.0f);
}

// K1: b<1024: bd[b] = dot(dec_z, mlp_dec_w[b,:]) + mlp_dec_b[b] + wvec_b[b]
//     b>=1024 (32 blocks): cov[l] = sum_p att_prev[p][l]; copy old rows to out
__global__ __launch_bounds__(256) void k_prep(
    const float* __restrict__ dec_z, const float* __restrict__ mlp_dec_w,
    const float* __restrict__ mlp_dec_b, const float* __restrict__ wvec_b,
    const float* __restrict__ att_prev,
    float* __restrict__ bd, float* __restrict__ cov, float* __restrict__ out_att)
{
    int b = blockIdx.x, t = threadIdx.x;
    if (b < 1024) {
        __shared__ float red[4];
        int wave = t >> 6, lane = t & 63;
        const float4* wrow = (const float4*)(mlp_dec_w + (size_t)b * ATT);
        const float4* dz   = (const float4*)dec_z;
        float4 wv = wrow[t], zv = dz[t];
        float s = wv.x * zv.x + wv.y * zv.y + wv.z * zv.z + wv.w * zv.w;
        #pragma unroll
        for (int off = 32; off; off >>= 1) s += __shfl_down(s, off, 64);
        if (lane == 0) red[wave] = s;
        __syncthreads();
        if (t == 0) bd[b] = red[0] + red[1] + red[2] + red[3]
                            + mlp_dec_b[b] + wvec_b[b];
    } else {
        int l = (b - 1024) * 256 + t;
        float s = 0.f;
        #pragma unroll
        for (int p = 0; p < NPREV; ++p) {
            float v = att_prev[p * L + l];
            out_att[p * L + l] = v;
            s += v;
        }
        cov[l] = s;
    }
}

// K2: 2048 blocks x 256 thr. Wave w scores row b*4+w (xor-butterfly so all
// lanes hold the sum), computes unnormalized u = exp(2e); one barrier; then
// all 256 threads do the coalesced 4-row ctx partial.
__global__ __launch_bounds__(256, 8) void k_score_ctx(
    const float* __restrict__ pre_enc, const float* __restrict__ enc_h,
    const float* __restrict__ cov, const float* __restrict__ wvec_w,
    const float* __restrict__ bd, const float* __restrict__ gvec_w,
    const float* __restrict__ gvec_b, const float* __restrict__ mask,
    float* __restrict__ u_out,    // out_att row 8 (unnormalized)
    float* __restrict__ usum,     // [K2B]
    float* __restrict__ partial)  // [K2B][ATT]
{
    __shared__ float uv_s[4];
    int t = threadIdx.x, b = blockIdx.x;
    int wave = t >> 6, lane = t & 63;
    int base = b * 4;
    int l = base + wave;

    float cv = cov[l];
    const float4* row = (const float4*)(pre_enc + (size_t)l * ATT);
    const float4* ww  = (const float4*)wvec_w;
    const float4* bdv = (const float4*)bd;
    const float4* gw  = (const float4*)gvec_w;
    float s = 0.f;
    #pragma unroll
    for (int k = 0; k < 4; ++k) {
        int i = lane + 64 * k;
        float4 pe = row[i];
        float4 w4 = ww[i], b4 = bdv[i], g4 = gw[i];
        s += fast_tanh(fmaf(cv, w4.x, b4.x) + pe.x) * g4.x;
        s += fast_tanh(fmaf(cv, w4.y, b4.y) + pe.y) * g4.y;
        s += fast_tanh(fmaf(cv, w4.z, b4.z) + pe.z) * g4.z;
        s += fast_tanh(fmaf(cv, w4.w, b4.w) + pe.w) * g4.w;
    }
    #pragma unroll
    for (int off = 32; off; off >>= 1) s += __shfl_xor(s, off, 64);
    // |2(s+gb+mask)| <= 2*sum|gvec_w| ~ 33 -> exp safe in f32, no max pass
    float uv = __expf(2.0f * (s + gvec_b[0] + mask[l]));
    if (lane == 0) { u_out[l] = uv; uv_s[wave] = uv; }
    __syncthreads();

    float u0 = uv_s[0], u1 = uv_s[1], u2 = uv_s[2], u3 = uv_s[3];
    const float4* enc = (const float4*)enc_h;
    float4 v0 = enc[(size_t)(base + 0) * 256 + t];
    float4 v1 = enc[(size_t)(base + 1) * 256 + t];
    float4 v2 = enc[(size_t)(base + 2) * 256 + t];
    float4 v3 = enc[(size_t)(base + 3) * 256 + t];
    float4 a;
    a.x = u0 * v0.x + u1 * v1.x + u2 * v2.x + u3 * v3.x;
    a.y = u0 * v0.y + u1 * v1.y + u2 * v2.y + u3 * v3.y;
    a.z = u0 * v0.z + u1 * v1.z + u2 * v2.z + u3 * v3.z;
    a.w = u0 * v0.w + u1 * v1.w + u2 * v2.w + u3 * v3.w;
    ((float4*)partial)[(size_t)b * 256 + t] = a;
    if (t == 0) usum[b] = u0 + u1 + u2 + u3;
}

// K3: blocks 0..63 -> c (reduce K2B partial rows); 64..95 -> scale w in place
__global__ __launch_bounds__(256) void k_finalize(
    const float* __restrict__ usum, const float* __restrict__ partial,
    float* __restrict__ out_c, float* __restrict__ w_inplace)
{
    __shared__ float red[4];
    __shared__ float s_inv_sh;
    __shared__ float4 wred[4][4];
    int t = threadIdx.x, b = blockIdx.x;
    int wave = t >> 6, lane = t & 63;

    float v = 0.f;
    #pragma unroll
    for (int i = 0; i < K2B / 256; ++i) v += usum[t + 256 * i];
    #pragma unroll
    for (int off = 32; off; off >>= 1) v += __shfl_down(v, off, 64);
    if (lane == 0) red[wave] = v;
    __syncthreads();
    if (t == 0) s_inv_sh = 1.0f / (red[0] + red[1] + red[2] + red[3]);
    __syncthreads();
    float inv = s_inv_sh;

    if (b < 64) {
        int c = t & 3, r = t >> 2;   // 4 float4-cols x 64 row-threads
        const float4* p4 = (const float4*)partial;
        float4 a = {0.f, 0.f, 0.f, 0.f};
        #pragma unroll
        for (int i = 0; i < K2B / 64; ++i) {
            float4 vv = p4[(size_t)(r + 64 * i) * 256 + b * 4 + c];
            a.x += vv.x; a.y += vv.y; a.z += vv.z; a.w += vv.w;
        }
        #pragma unroll
        for (int off = 4; off <= 32; off <<= 1) {
            a.x += __shfl_xor(a.x, off, 64);
            a.y += __shfl_xor(a.y, off, 64);
            a.z += __shfl_xor(a.z, off, 64);
            a.w += __shfl_xor(a.w, off, 64);
        }
        if (lane < 4) wred[wave][lane] = a;
        __syncthreads();
        if (t < 4) {
            float4 s0 = wred[0][t], s1 = wred[1][t],
                   s2 = wred[2][t], s3 = wred[3][t];
            float4 o;
            o.x = (s0.x + s1.x + s2.x + s3.x) * inv;
            o.y = (s0.y + s1.y + s2.y + s3.y) * inv;
            o.z = (s0.z + s1.z + s2.z + s3.z) * inv;
            o.w = (s0.w + s1.w + s2.w + s3.w) * inv;
            ((float4*)out_c)[b * 4 + t] = o;
        }
    } else {
        w_inplace[(b - 64) * 256 + t] *= inv;
    }
}

extern "C" void kernel_launch(void* const* d_in, const int* in_sizes, int n_in,
                              void* d_out, int out_size, void* d_ws, size_t ws_size,
                              hipStream_t stream) {
    const float* dec_z     = (const float*)d_in[0];
    const float* att_prev  = (const float*)d_in[1];
    const float* pre_enc   = (const float*)d_in[2];
    const float* enc_h     = (const float*)d_in[3];
    const float* mask      = (const float*)d_in[4];
    const float* wvec_w    = (const float*)d_in[5];
    const float* wvec_b    = (const float*)d_in[6];
    const float* mlp_dec_w = (const float*)d_in[7];
    const float* mlp_dec_b = (const float*)d_in[8];
    const float* gvec_w    = (const float*)d_in[9];
    const float* gvec_b    = (const float*)d_in[10];

    float* out     = (float*)d_out;
    float* out_c   = out;          // [1024]
    float* out_att = out + 1024;   // [9*8192]
    float* out_w   = out_att + 8 * L;

    float* ws      = (float*)d_ws;
    float* bd      = ws;                              // 1024
    float* cov     = ws + 1024;                       // 8192
    float* usum    = ws + 1024 + 8192;                // 2048
    float* partial = ws + 1024 + 8192 + 2048;         // K2B*1024 (~8 MB)

    k_prep<<<1056, 256, 0, stream>>>(dec_z, mlp_dec_w, mlp_dec_b, wvec_b,
                                     att_prev, bd, cov, out_att);
    k_score_ctx<<<K2B, 256, 0, stream>>>(pre_enc, enc_h, cov, wvec_w, bd,
                                         gvec_w, gvec_b, mask,
                                         out_w, usum, partial);
    k_finalize<<<96, 256, 0, stream>>>(usum, partial, out_c, out_w);
}

// Round 8
// 27.109 us; speedup vs baseline: 1.3354x; 1.0417x over previous
//
#include <hip/hip_runtime.h>

#define L 8192
#define ATT 1024
#define NPREV 8

__device__ inline float fast_tanh(float x) {
    // tanh(x) = 1 - 2/(exp(2x)+1); saturates correctly
    float e = __expf(2.0f * x);
    return 1.0f - 2.0f / (e + 1.0f);
}

// K1: b<1024: bd[b] = dot(dec_z, mlp_dec_w[b,:]) + mlp_dec_b[b] + wvec_b[b]
//     b>=1024 (32 blocks): cov[l] = sum_p att_prev[p][l]; copy old rows to out
__global__ __launch_bounds__(256) void k_prep(
    const float* __restrict__ dec_z, const float* __restrict__ mlp_dec_w,
    const float* __restrict__ mlp_dec_b, const float* __restrict__ wvec_b,
    const float* __restrict__ att_prev,
    float* __restrict__ bd, float* __restrict__ cov, float* __restrict__ out_att)
{
    int b = blockIdx.x, t = threadIdx.x;
    if (b < 1024) {
        __shared__ float red[4];
        int wave = t >> 6, lane = t & 63;
        const float4* wrow = (const float4*)(mlp_dec_w + (size_t)b * ATT);
        const float4* dz   = (const float4*)dec_z;
        float4 wv = wrow[t], zv = dz[t];
        float s = wv.x * zv.x + wv.y * zv.y + wv.z * zv.z + wv.w * zv.w;
        #pragma unroll
        for (int off = 32; off; off >>= 1) s += __shfl_down(s, off, 64);
        if (lane == 0) red[wave] = s;
        __syncthreads();
        if (t == 0) bd[b] = red[0] + red[1] + red[2] + red[3]
                            + mlp_dec_b[b] + wvec_b[b];
    } else {
        int l = (b - 1024) * 256 + t;
        float s = 0.f;
        #pragma unroll
        for (int p = 0; p < NPREV; ++p) {
            float v = att_prev[p * L + l];
            out_att[p * L + l] = v;
            s += v;
        }
        cov[l] = s;
    }
}

// K2: 256 blocks x 1024 thr (16 waves). Wave scores 2 rows; enc_h loads are
// issued BEFORE the tanh/butterfly chain (independent of uv) so they overlap
// the serial reduction; ctx FMAs consume them after uv is known.
__global__ __launch_bounds__(1024) void k_score_ctx(
    const float* __restrict__ pre_enc, const float* __restrict__ enc_h,
    const float* __restrict__ cov, const float* __restrict__ wvec_w,
    const float* __restrict__ bd, const float* __restrict__ gvec_w,
    const float* __restrict__ gvec_b, const float* __restrict__ mask,
    float* __restrict__ u_out,    // out_att row 8 (unnormalized)
    float* __restrict__ usum,     // [256]
    float* __restrict__ partial)  // [256][ATT]
{
    __shared__ float lds[8 * 1024];
    __shared__ float uw[16];
    int t = threadIdx.x, b = blockIdx.x;
    int base = b * 32;
    int wave = t >> 6, lane = t & 63;

    const float4* ww  = (const float4*)wvec_w;
    const float4* bdv = (const float4*)bd;
    const float4* gw  = (const float4*)gvec_w;
    float4 W4[4], BD4[4], G4[4];
    #pragma unroll
    for (int k = 0; k < 4; ++k) {
        W4[k]  = ww[lane + 64 * k];
        BD4[k] = bdv[lane + 64 * k];
        G4[k]  = gw[lane + 64 * k];
    }
    float gb = gvec_b[0];

    const float4* enc = (const float4*)enc_h;
    float4 acc[4] = {};
    float us_w = 0.f;
    #pragma unroll
    for (int rr = 0; rr < 2; ++rr) {
        int l = base + wave * 2 + rr;
        float cv = cov[l];
        const float4* row = (const float4*)(pre_enc + (size_t)l * ATT);
        float4 pe[4], ev[4];
        #pragma unroll
        for (int k = 0; k < 4; ++k) pe[k] = row[lane + 64 * k];
        #pragma unroll
        for (int k = 0; k < 4; ++k) ev[k] = enc[(size_t)l * 256 + 64 * k + lane];
        float s = 0.f;
        #pragma unroll
        for (int k = 0; k < 4; ++k) {
            s += fast_tanh(fmaf(cv, W4[k].x, BD4[k].x) + pe[k].x) * G4[k].x;
            s += fast_tanh(fmaf(cv, W4[k].y, BD4[k].y) + pe[k].y) * G4[k].y;
            s += fast_tanh(fmaf(cv, W4[k].z, BD4[k].z) + pe[k].z) * G4[k].z;
            s += fast_tanh(fmaf(cv, W4[k].w, BD4[k].w) + pe[k].w) * G4[k].w;
        }
        #pragma unroll
        for (int off = 32; off; off >>= 1) s += __shfl_xor(s, off, 64);
        // |2(s+gb+mask)| <= 2*sum|gvec_w| ~ 33 -> exp safe in f32, no max pass
        float uv = __expf(2.0f * (s + gb + mask[l]));
        if (lane == 0) { u_out[l] = uv; us_w += uv; }
        #pragma unroll
        for (int k = 0; k < 4; ++k) {
            acc[k].x += uv * ev[k].x; acc[k].y += uv * ev[k].y;
            acc[k].z += uv * ev[k].z; acc[k].w += uv * ev[k].w;
        }
    }
    if (lane == 0) uw[wave] = us_w;

    // cross-wave combine: waves 8..15 stage, 0..7 add, then 1024 thr fold 8
    float4* la = (float4*)lds;
    if (wave >= 8) {
        #pragma unroll
        for (int k = 0; k < 4; ++k)
            la[(wave - 8) * 256 + k * 64 + lane] = acc[k];
    }
    __syncthreads();
    if (wave < 8) {
        #pragma unroll
        for (int k = 0; k < 4; ++k) {
            float4 o = la[wave * 256 + k * 64 + lane];
            o.x += acc[k].x; o.y += acc[k].y;
            o.z += acc[k].z; o.w += acc[k].w;
            la[wave * 256 + k * 64 + lane] = o;
        }
    }
    __syncthreads();
    {
        float s = 0.f;
        #pragma unroll
        for (int w = 0; w < 8; ++w) s += lds[w * 1024 + t];
        partial[(size_t)b * 1024 + t] = s;
    }
    if (t == 0) {
        float s = 0.f;
        #pragma unroll
        for (int w = 0; w < 16; ++w) s += uw[w];
        usum[b] = s;
    }
}

// K3: 48 blocks. b<16: c columns (coalesced 256B wave reads over 256 partial
// rows); b in 16..47: scale w in place.
__global__ __launch_bounds__(256) void k_finalize(
    const float* __restrict__ usum, const float* __restrict__ partial,
    float* __restrict__ out_c, float* __restrict__ w_inplace)
{
    __shared__ float red[4];
    __shared__ float s_inv_sh;
    __shared__ float cred[256];
    int t = threadIdx.x, b = blockIdx.x;
    int wave = t >> 6, lane = t & 63;

    float v = usum[t];
    #pragma unroll
    for (int off = 32; off; off >>= 1) v += __shfl_down(v, off, 64);
    if (lane == 0) red[wave] = v;
    __syncthreads();
    if (t == 0) s_inv_sh = 1.0f / (red[0] + red[1] + red[2] + red[3]);
    __syncthreads();
    float inv = s_inv_sh;

    if (b < 16) {
        int j = b * 64 + (t & 63);
        int r0 = t >> 6;                    // 4 row-groups
        float s = 0.f;
        #pragma unroll 8
        for (int k = 0; k < 64; ++k)
            s += partial[(size_t)(r0 + 4 * k) * 1024 + j];
        cred[t] = s;
        __syncthreads();
        if (t < 128) cred[t] += cred[t + 128];
        __syncthreads();
        if (t < 64) out_c[b * 64 + t] = (cred[t] + cred[t + 64]) * inv;
    } else {
        w_inplace[(b - 16) * 256 + t] *= inv;
    }
}

extern "C" void kernel_launch(void* const* d_in, const int* in_sizes, int n_in,
                              void* d_out, int out_size, void* d_ws, size_t ws_size,
                              hipStream_t stream) {
    const float* dec_z     = (const float*)d_in[0];
    const float* att_prev  = (const float*)d_in[1];
    const float* pre_enc   = (const float*)d_in[2];
    const float* enc_h     = (const float*)d_in[3];
    const float* mask      = (const float*)d_in[4];
    const float* wvec_w    = (const float*)d_in[5];
    const float* wvec_b    = (const float*)d_in[6];
    const float* mlp_dec_w = (const float*)d_in[7];
    const float* mlp_dec_b = (const float*)d_in[8];
    const float* gvec_w    = (const float*)d_in[9];
    const float* gvec_b    = (const float*)d_in[10];

    float* out     = (float*)d_out;
    float* out_c   = out;          // [1024]
    float* out_att = out + 1024;   // [9*8192]
    float* out_w   = out_att + 8 * L;

    float* ws      = (float*)d_ws;
    float* bd      = ws;                        // 1024
    float* cov     = ws + 1024;                 // 8192
    float* usum    = ws + 1024 + 8192;          // 256
    float* partial = ws + 1024 + 8192 + 256;    // 256*1024 (~1 MB)

    k_prep<<<1056, 256, 0, stream>>>(dec_z, mlp_dec_w, mlp_dec_b, wvec_b,
                                     att_prev, bd, cov, out_att);
    k_score_ctx<<<256, 1024, 0, stream>>>(pre_enc, enc_h, cov, wvec_w, bd,
                                          gvec_w, gvec_b, mask,
                                          out_w, usum, partial);
    k_finalize<<<48, 256, 0, stream>>>(usum, partial, out_c, out_w);
}

// Round 9
// 25.437 us; speedup vs baseline: 1.4232x; 1.0658x over previous
//
#include <hip/hip_runtime.h>

#define L 8192
#define ATT 1024
#define NPREV 8
#define NB 512   // K2 blocks: 512x512thr, 2 blocks/CU, 16 waves/CU

__device__ inline float fast_tanh(float x) {
    // tanh(x) = 1 - 2/(exp(2x)+1); saturates correctly
    float e = __expf(2.0f * x);
    return 1.0f - 2.0f / (e + 1.0f);
}

// K1: b<1024: bd[b] = dot(dec_z, mlp_dec_w[b,:]) + mlp_dec_b[b] + wvec_b[b]
//     b>=1024 (32 blocks): cov[l] = sum_p att_prev[p][l]; copy old rows to out
__global__ __launch_bounds__(256) void k_prep(
    const float* __restrict__ dec_z, const float* __restrict__ mlp_dec_w,
    const float* __restrict__ mlp_dec_b, const float* __restrict__ wvec_b,
    const float* __restrict__ att_prev,
    float* __restrict__ bd, float* __restrict__ cov, float* __restrict__ out_att)
{
    int b = blockIdx.x, t = threadIdx.x;
    if (b < 1024) {
        __shared__ float red[4];
        int wave = t >> 6, lane = t & 63;
        const float4* wrow = (const float4*)(mlp_dec_w + (size_t)b * ATT);
        const float4* dz   = (const float4*)dec_z;
        float4 wv = wrow[t], zv = dz[t];
        float s = wv.x * zv.x + wv.y * zv.y + wv.z * zv.z + wv.w * zv.w;
        #pragma unroll
        for (int off = 32; off; off >>= 1) s += __shfl_down(s, off, 64);
        if (lane == 0) red[wave] = s;
        __syncthreads();
        if (t == 0) bd[b] = red[0] + red[1] + red[2] + red[3]
                            + mlp_dec_b[b] + wvec_b[b];
    } else {
        int l = (b - 1024) * 256 + t;
        float s = 0.f;
        #pragma unroll
        for (int p = 0; p < NPREV; ++p) {
            float v = att_prev[p * L + l];
            out_att[p * L + l] = v;
            s += v;
        }
        cov[l] = s;
    }
}

// K2: 512 blocks x 512 thr (8 waves), 2 rows/wave. Per row: issue pe[4]+ev[4]
// (8 outstanding 16B loads/lane) BEFORE the tanh/butterfly chain; ctx FMAs
// consume ev after uv is known. VGPR ~110 < 128 cap -> 16 waves/CU holds.
__global__ __launch_bounds__(512, 4) void k_score_ctx(
    const float* __restrict__ pre_enc, const float* __restrict__ enc_h,
    const float* __restrict__ cov, const float* __restrict__ wvec_w,
    const float* __restrict__ bd, const float* __restrict__ gvec_w,
    const float* __restrict__ gvec_b, const float* __restrict__ mask,
    float* __restrict__ u_out,    // out_att row 8 (unnormalized)
    float* __restrict__ usum,     // [NB]
    float* __restrict__ partial)  // [NB][ATT]
{
    __shared__ float lds[4 * 1024];
    __shared__ float uw[8];
    int t = threadIdx.x, b = blockIdx.x;
    int base = b * 16;
    int wave = t >> 6, lane = t & 63;

    const float4* ww  = (const float4*)wvec_w;
    const float4* bdv = (const float4*)bd;
    const float4* gw  = (const float4*)gvec_w;
    float4 W4[4], BD4[4], G4[4];
    #pragma unroll
    for (int k = 0; k < 4; ++k) {
        W4[k]  = ww[lane + 64 * k];
        BD4[k] = bdv[lane + 64 * k];
        G4[k]  = gw[lane + 64 * k];
    }
    float gb = gvec_b[0];

    const float4* enc = (const float4*)enc_h;
    float4 acc[4] = {};
    float us_w = 0.f;
    #pragma unroll
    for (int rr = 0; rr < 2; ++rr) {
        int l = base + wave * 2 + rr;
        float cv = cov[l];
        const float4* row = (const float4*)(pre_enc + (size_t)l * ATT);
        float4 pe[4], ev[4];
        #pragma unroll
        for (int k = 0; k < 4; ++k) pe[k] = row[lane + 64 * k];
        #pragma unroll
        for (int k = 0; k < 4; ++k) ev[k] = enc[(size_t)l * 256 + 64 * k + lane];
        float s = 0.f;
        #pragma unroll
        for (int k = 0; k < 4; ++k) {
            s += fast_tanh(fmaf(cv, W4[k].x, BD4[k].x) + pe[k].x) * G4[k].x;
            s += fast_tanh(fmaf(cv, W4[k].y, BD4[k].y) + pe[k].y) * G4[k].y;
            s += fast_tanh(fmaf(cv, W4[k].z, BD4[k].z) + pe[k].z) * G4[k].z;
            s += fast_tanh(fmaf(cv, W4[k].w, BD4[k].w) + pe[k].w) * G4[k].w;
        }
        #pragma unroll
        for (int off = 32; off; off >>= 1) s += __shfl_xor(s, off, 64);
        // |2(s+gb+mask)| <= 2*sum|gvec_w| ~ 33 -> exp safe in f32, no max pass
        float uv = __expf(2.0f * (s + gb + mask[l]));
        if (lane == 0) { u_out[l] = uv; us_w += uv; }
        #pragma unroll
        for (int k = 0; k < 4; ++k) {
            acc[k].x += uv * ev[k].x; acc[k].y += uv * ev[k].y;
            acc[k].z += uv * ev[k].z; acc[k].w += uv * ev[k].w;
        }
    }
    if (lane == 0) uw[wave] = us_w;

    // cross-wave combine: waves 4..7 stage, 0..3 add, then 512 thr fold 4 rows
    float4* la = (float4*)lds;
    if (wave >= 4) {
        #pragma unroll
        for (int k = 0; k < 4; ++k)
            la[(wave - 4) * 256 + k * 64 + lane] = acc[k];
    }
    __syncthreads();
    if (wave < 4) {
        #pragma unroll
        for (int k = 0; k < 4; ++k) {
            float4 o = la[wave * 256 + k * 64 + lane];
            o.x += acc[k].x; o.y += acc[k].y;
            o.z += acc[k].z; o.w += acc[k].w;
            la[wave * 256 + k * 64 + lane] = o;
        }
    }
    __syncthreads();
    #pragma unroll
    for (int cc = 0; cc < 2; ++cc) {
        int col = t + cc * 512;
        partial[(size_t)b * 1024 + col] =
            lds[col] + lds[1024 + col] + lds[2048 + col] + lds[3072 + col];
    }
    if (t == 0) {
        float s = 0.f;
        #pragma unroll
        for (int w = 0; w < 8; ++w) s += uw[w];
        usum[b] = s;
    }
}

// K3: blocks 0..63 -> c (reduce NB partial rows); 64..95 -> scale w in place
__global__ __launch_bounds__(256) void k_finalize(
    const float* __restrict__ usum, const float* __restrict__ partial,
    float* __restrict__ out_c, float* __restrict__ w_inplace)
{
    __shared__ float red[4];
    __shared__ float s_inv_sh;
    __shared__ float4 wred[4][4];
    int t = threadIdx.x, b = blockIdx.x;
    int wave = t >> 6, lane = t & 63;

    float v = 0.f;
    #pragma unroll
    for (int i = 0; i < NB / 256; ++i) v += usum[t + 256 * i];
    #pragma unroll
    for (int off = 32; off; off >>= 1) v += __shfl_down(v, off, 64);
    if (lane == 0) red[wave] = v;
    __syncthreads();
    if (t == 0) s_inv_sh = 1.0f / (red[0] + red[1] + red[2] + red[3]);
    __syncthreads();
    float inv = s_inv_sh;

    if (b < 64) {
        int c = t & 3, r = t >> 2;   // 4 float4-cols x 64 row-threads
        const float4* p4 = (const float4*)partial;
        float4 a = {0.f, 0.f, 0.f, 0.f};
        #pragma unroll
        for (int i = 0; i < NB / 64; ++i) {
            float4 vv = p4[(size_t)(r + 64 * i) * 256 + b * 4 + c];
            a.x += vv.x; a.y += vv.y; a.z += vv.z; a.w += vv.w;
        }
        #pragma unroll
        for (int off = 4; off <= 32; off <<= 1) {
            a.x += __shfl_xor(a.x, off, 64);
            a.y += __shfl_xor(a.y, off, 64);
            a.z += __shfl_xor(a.z, off, 64);
            a.w += __shfl_xor(a.w, off, 64);
        }
        if (lane < 4) wred[wave][lane] = a;
        __syncthreads();
        if (t < 4) {
            float4 s0 = wred[0][t], s1 = wred[1][t],
                   s2 = wred[2][t], s3 = wred[3][t];
            float4 o;
            o.x = (s0.x + s1.x + s2.x + s3.x) * inv;
            o.y = (s0.y + s1.y + s2.y + s3.y) * inv;
            o.z = (s0.z + s1.z + s2.z + s3.z) * inv;
            o.w = (s0.w + s1.w + s2.w + s3.w) * inv;
            ((float4*)out_c)[b * 4 + t] = o;
        }
    } else {
        w_inplace[(b - 64) * 256 + t] *= inv;
    }
}

extern "C" void kernel_launch(void* const* d_in, const int* in_sizes, int n_in,
                              void* d_out, int out_size, void* d_ws, size_t ws_size,
                              hipStream_t stream) {
    const float* dec_z     = (const float*)d_in[0];
    const float* att_prev  = (const float*)d_in[1];
    const float* pre_enc   = (const float*)d_in[2];
    const float* enc_h     = (const float*)d_in[3];
    const float* mask      = (const float*)d_in[4];
    const float* wvec_w    = (const float*)d_in[5];
    const float* wvec_b    = (const float*)d_in[6];
    const float* mlp_dec_w = (const float*)d_in[7];
    const float* mlp_dec_b = (const float*)d_in[8];
    const float* gvec_w    = (const float*)d_in[9];
    const float* gvec_b    = (const float*)d_in[10];

    float* out     = (float*)d_out;
    float* out_c   = out;          // [1024]
    float* out_att = out + 1024;   // [9*8192]
    float* out_w   = out_att + 8 * L;

    float* ws      = (float*)d_ws;
    float* bd      = ws;                        // 1024
    float* cov     = ws + 1024;                 // 8192
    float* usum    = ws + 1024 + 8192;          // 512
    float* partial = ws + 1024 + 8192 + 512;    // NB*1024 (~2 MB)

    k_prep<<<1056, 256, 0, stream>>>(dec_z, mlp_dec_w, mlp_dec_b, wvec_b,
                                     att_prev, bd, cov, out_att);
    k_score_ctx<<<NB, 512, 0, stream>>>(pre_enc, enc_h, cov, wvec_w, bd,
                                        gvec_w, gvec_b, mask,
                                        out_w, usum, partial);
    k_finalize<<<96, 256, 0, stream>>>(usum, partial, out_c, out_w);
}